// Round 6
// baseline (150.246 us; speedup 1.0000x reference)
//
#include <hip/hip_runtime.h>
#include <hip/hip_fp16.h>

#define N_CLASS_C 6

typedef int vint4 __attribute__((ext_vector_type(4)));

// 8-byte packed atom record: fp16 x,y,z,radius. One dwordx2 gather per atom.
struct alignas(8) HAtom {
    __half x, y, z, r;
};

__global__ void zero_accum(float* accum) {
    if (threadIdx.x < N_CLASS_C) accum[threadIdx.x] = 0.0f;
}

__global__ void prep_atoms(const float* __restrict__ coords,
                           const float* __restrict__ radii,
                           const int* __restrict__ names,
                           HAtom* __restrict__ atoms,
                           int n_atoms) {
    int i = blockIdx.x * blockDim.x + threadIdx.x;
    if (i < n_atoms) {
        HAtom a;
        a.x = __float2half(coords[3 * i + 0]);
        a.y = __float2half(coords[3 * i + 1]);
        a.z = __float2half(coords[3 * i + 2]);
        a.r = __float2half(radii[names[i]]);
        atoms[i] = a;
    }
}

__device__ __forceinline__ void block_reduce_accum(float* s, float* accum) {
    __shared__ float sh[N_CLASS_C];
    if (threadIdx.x < N_CLASS_C) sh[threadIdx.x] = 0.0f;
    __syncthreads();
#pragma unroll
    for (int c = 0; c < N_CLASS_C; ++c) {
        float v = s[c];
#pragma unroll
        for (int off = 32; off > 0; off >>= 1) v += __shfl_down(v, off, 64);
        if ((threadIdx.x & 63) == 0 && v != 0.0f) atomicAdd(&sh[c], v);
    }
    __syncthreads();
    if (threadIdx.x < N_CLASS_C) {
        float v = sh[threadIdx.x];
        if (v != 0.0f) atomicAdd(&accum[threadIdx.x], v);
    }
}

__device__ __forceinline__ void block_reduce_one(float v, float* dst) {
    __shared__ float sh1;
    if (threadIdx.x == 0) sh1 = 0.0f;
    __syncthreads();
#pragma unroll
    for (int off = 32; off > 0; off >>= 1) v += __shfl_down(v, off, 64);
    if ((threadIdx.x & 63) == 0) atomicAdd(&sh1, v);
    __syncthreads();
    if (threadIdx.x == 0) atomicAdd(dst, sh1);
}

__device__ __forceinline__ float hdist_base(const HAtom& A, const HAtom& B) {
    float dx = __half2float(A.x) - __half2float(B.x);
    float dy = __half2float(A.y) - __half2float(B.y);
    float dz = __half2float(A.z) - __half2float(B.z);
    float dist = sqrtf(dx * dx + dy * dy + dz * dz + 1e-12f);
    return (__half2float(A.r) + __half2float(B.r)) - dist;
}

#define K_GRP 2

// VARIANT 0: real kernel (round-5 structure). Writes accum.
// VARIANT 1: pairs + both gathers + distance, NO mask branch. Writes scratch.
// VARIANT 2: pairs only, fake compute. Writes scratch.
// VARIANT 3: pairs + A-side gathers only (half requests). Writes scratch.
template <int VARIANT>
__global__ __launch_bounds__(256) void clash_var(
    const int* __restrict__ pairs,      // 2 * n_pairs
    const HAtom* __restrict__ atoms,
    const int* __restrict__ masks,      // N_CLASS * n_pairs
    const float* __restrict__ tol,
    float* __restrict__ accum,
    float* __restrict__ scratch,
    int n_pairs, int T, int ngroups) {
    float tc[N_CLASS_C];
#pragma unroll
    for (int c = 0; c < N_CLASS_C; ++c) tc[c] = tol[c];
    float tmax = tc[0];
#pragma unroll
    for (int c = 1; c < N_CLASS_C; ++c) tmax = fmaxf(tmax, tc[c]);

    float s[N_CLASS_C];
#pragma unroll
    for (int c = 0; c < N_CLASS_C; ++c) s[c] = 0.0f;
    float bsum = 0.0f;

    const int tid = blockIdx.x * blockDim.x + threadIdx.x;
    const vint4* pairs4 = reinterpret_cast<const vint4*>(pairs);

    if (tid < T) {
        vint4 pa[K_GRP], pb[K_GRP];
#pragma unroll
        for (int k = 0; k < K_GRP; ++k) {
            int g = tid + k * T;
            pa[k] = pairs4[2 * g];
            pb[k] = pairs4[2 * g + 1];
        }
        __builtin_amdgcn_sched_barrier(0);

        if (VARIANT == 2) {
            // stream floor: consume indices with VALU only
#pragma unroll
            for (int k = 0; k < K_GRP; ++k) {
                bsum += (float)(pa[k].x + pa[k].y + pa[k].z + pa[k].w +
                                pb[k].x + pb[k].y + pb[k].z + pb[k].w) * 1e-30f;
            }
        } else if (VARIANT == 3) {
            // half-request probe: A-side gathers only
            HAtom A[K_GRP][4];
#pragma unroll
            for (int k = 0; k < K_GRP; ++k) {
                int i0[4] = {pa[k].x, pa[k].z, pb[k].x, pb[k].z};
#pragma unroll
                for (int j = 0; j < 4; ++j) A[k][j] = atoms[i0[j]];
            }
            __builtin_amdgcn_sched_barrier(0);
#pragma unroll
            for (int k = 0; k < K_GRP; ++k)
#pragma unroll
                for (int j = 0; j < 4; ++j)
                    bsum += __half2float(A[k][j].x) + __half2float(A[k][j].y) +
                            __half2float(A[k][j].z) + __half2float(A[k][j].r);
        } else {
            // VARIANT 0 and 1: full gathers
            HAtom A[K_GRP][4], B[K_GRP][4];
#pragma unroll
            for (int k = 0; k < K_GRP; ++k) {
                int i0[4] = {pa[k].x, pa[k].z, pb[k].x, pb[k].z};
                int i1[4] = {pa[k].y, pa[k].w, pb[k].y, pb[k].w};
#pragma unroll
                for (int j = 0; j < 4; ++j) {
                    A[k][j] = atoms[i0[j]];
                    B[k][j] = atoms[i1[j]];
                }
            }
            __builtin_amdgcn_sched_barrier(0);
#pragma unroll
            for (int k = 0; k < K_GRP; ++k) {
                float base[4];
#pragma unroll
                for (int j = 0; j < 4; ++j) base[j] = hdist_base(A[k][j], B[k][j]);
                if (VARIANT == 1) {
                    bsum += base[0] + base[1] + base[2] + base[3];
                } else {
                    float bm = fmaxf(fmaxf(base[0], base[1]), fmaxf(base[2], base[3]));
                    if (bm + tmax > 0.0f) {
                        int g = tid + k * T;
#pragma unroll
                        for (int c = 0; c < N_CLASS_C; ++c) {
                            const int* mrow = masks + (size_t)c * n_pairs + 4 * (size_t)g;
                            float acc = 0.0f;
                            if (mrow[0]) acc += fmaxf(base[0] + tc[c], 0.0f);
                            if (mrow[1]) acc += fmaxf(base[1] + tc[c], 0.0f);
                            if (mrow[2]) acc += fmaxf(base[2] + tc[c], 0.0f);
                            if (mrow[3]) acc += fmaxf(base[3] + tc[c], 0.0f);
                            s[c] += acc;
                        }
                    }
                }
            }
        }
    }

    if (VARIANT == 0) {
        // Leftover groups [K*T, ngroups)
        int g = K_GRP * T + tid;
        if (g < ngroups) {
            vint4 pa = pairs4[2 * g];
            vint4 pb = pairs4[2 * g + 1];
            int i0[4] = {pa.x, pa.z, pb.x, pb.z};
            int i1[4] = {pa.y, pa.w, pb.y, pb.w};
            float base[4];
#pragma unroll
            for (int j = 0; j < 4; ++j) base[j] = hdist_base(atoms[i0[j]], atoms[i1[j]]);
            float bm = fmaxf(fmaxf(base[0], base[1]), fmaxf(base[2], base[3]));
            if (bm + tmax > 0.0f) {
#pragma unroll
                for (int c = 0; c < N_CLASS_C; ++c) {
                    const int* mrow = masks + (size_t)c * n_pairs + 4 * (size_t)g;
                    float acc = 0.0f;
                    if (mrow[0]) acc += fmaxf(base[0] + tc[c], 0.0f);
                    if (mrow[1]) acc += fmaxf(base[1] + tc[c], 0.0f);
                    if (mrow[2]) acc += fmaxf(base[2] + tc[c], 0.0f);
                    if (mrow[3]) acc += fmaxf(base[3] + tc[c], 0.0f);
                    s[c] += acc;
                }
            }
        }
        // Leftover pairs [4*ngroups, n_pairs)
        int p = 4 * ngroups + tid;
        if (p < n_pairs) {
            int a0 = pairs[2 * p], a1 = pairs[2 * p + 1];
            float base = hdist_base(atoms[a0], atoms[a1]);
            if (base + tmax > 0.0f) {
#pragma unroll
                for (int c = 0; c < N_CLASS_C; ++c) {
                    if (masks[(size_t)c * n_pairs + p])
                        s[c] += fmaxf(base + tc[c], 0.0f);
                }
            }
        }
        block_reduce_accum(s, accum);
    } else {
        block_reduce_one(bsum, scratch);
    }
}

__global__ void finalize(const float* __restrict__ accum,
                         const float* __restrict__ w,
                         float* __restrict__ out) {
    int c = threadIdx.x;
    if (c < N_CLASS_C) {
        float scale = expf(w[0]);
        out[c] = accum[c] * scale;
    }
}

// -------- fallback (tiny ws): direct gather path, fp32, no atoms table --------
__global__ __launch_bounds__(256) void clash_fallback(
    const int* __restrict__ pairs,
    const float* __restrict__ coords,
    const float* __restrict__ radii,
    const int* __restrict__ names,
    const int* __restrict__ masks,
    const float* __restrict__ tol,
    float* __restrict__ accum,
    int n_pairs) {
    float tc[N_CLASS_C];
#pragma unroll
    for (int c = 0; c < N_CLASS_C; ++c) tc[c] = tol[c];
    float tmax = tc[0];
#pragma unroll
    for (int c = 1; c < N_CLASS_C; ++c) tmax = fmaxf(tmax, tc[c]);
    float s[N_CLASS_C];
#pragma unroll
    for (int c = 0; c < N_CLASS_C; ++c) s[c] = 0.0f;

    const int tid = blockIdx.x * blockDim.x + threadIdx.x;
    const int stride = gridDim.x * blockDim.x;
    for (int p = tid; p < n_pairs; p += stride) {
        int a0 = pairs[2 * p], a1 = pairs[2 * p + 1];
        float dx = coords[3 * a0] - coords[3 * a1];
        float dy = coords[3 * a0 + 1] - coords[3 * a1 + 1];
        float dz = coords[3 * a0 + 2] - coords[3 * a1 + 2];
        float dist = sqrtf(dx * dx + dy * dy + dz * dz + 1e-12f);
        float base = (radii[names[a0]] + radii[names[a1]]) - dist;
        if (base + tmax > 0.0f) {
#pragma unroll
            for (int c = 0; c < N_CLASS_C; ++c) {
                if (masks[(size_t)c * n_pairs + p])
                    s[c] += fmaxf(base + tc[c], 0.0f);
            }
        }
    }
    block_reduce_accum(s, accum);
}

extern "C" void kernel_launch(void* const* d_in, const int* in_sizes, int n_in,
                              void* d_out, int out_size, void* d_ws, size_t ws_size,
                              hipStream_t stream) {
    const float* coords = (const float*)d_in[0];
    const float* radii  = (const float*)d_in[1];
    const float* tol    = (const float*)d_in[2];
    const float* weight = (const float*)d_in[3];
    const int* names    = (const int*)d_in[4];
    const int* pairs    = (const int*)d_in[5];
    const int* masks    = (const int*)d_in[6];
    float* out = (float*)d_out;

    int n_atoms = in_sizes[4];
    int n_pairs = in_sizes[5] / 2;

    const size_t hdr_bytes = 256;
    size_t atoms_bytes = (size_t)n_atoms * sizeof(HAtom);

    if (ws_size >= hdr_bytes + atoms_bytes) {
        float* accum = (float*)d_ws;
        float* scratch = (float*)((char*)d_ws + 64);  // diagnostic sink
        HAtom* atoms = (HAtom*)((char*)d_ws + hdr_bytes);

        prep_atoms<<<(n_atoms + 255) / 256, 256, 0, stream>>>(coords, radii, names, atoms, n_atoms);
        zero_accum<<<1, 64, 0, stream>>>(accum);

        int ngroups = n_pairs >> 2;
        int T = ngroups / K_GRP;
        int nthreads = T > 0 ? T : 256;
        int blocks = (nthreads + 255) / 256;

        // Real kernel (produces output)
        clash_var<0><<<blocks, 256, 0, stream>>>(pairs, atoms, masks, tol, accum,
                                                 scratch, n_pairs, T, ngroups);
        // Diagnostic ablations (write to scratch only)
        clash_var<1><<<blocks, 256, 0, stream>>>(pairs, atoms, masks, tol, accum,
                                                 scratch, n_pairs, T, ngroups);
        clash_var<2><<<blocks, 256, 0, stream>>>(pairs, atoms, masks, tol, accum,
                                                 scratch, n_pairs, T, ngroups);
        clash_var<3><<<blocks, 256, 0, stream>>>(pairs, atoms, masks, tol, accum,
                                                 scratch, n_pairs, T, ngroups);

        finalize<<<1, 64, 0, stream>>>(accum, weight, out);
    } else {
        float* accum = out;
        zero_accum<<<1, 64, 0, stream>>>(accum);
        clash_fallback<<<2048, 256, 0, stream>>>(pairs, coords, radii, names,
                                                 masks, tol, accum, n_pairs);
        finalize<<<1, 64, 0, stream>>>(accum, weight, out);
    }
}

// Round 7
// 39.936 us; speedup vs baseline: 3.7622x; 3.7622x over previous
//
#include <hip/hip_runtime.h>
#include <hip/hip_fp16.h>

#define N_CLASS_C 6
#define MAX_WORDS 33344          // cell-table words; supports n_atoms <= 100,032
#define FILTER_BLOCK 1024
#define FILTER_GRID 256

typedef int vint2 __attribute__((ext_vector_type(2)));

// 8-byte packed atom record: fp16 x,y,z,radius. One dwordx2 gather per atom.
struct alignas(8) HAtom {
    __half x, y, z, r;
};

__global__ void zero_accum(float* accum) {
    if (threadIdx.x < N_CLASS_C) accum[threadIdx.x] = 0.0f;
}

// w = cell width = max possible clash distance (+margin), computed on device.
__global__ void compute_w(const float* __restrict__ radii, int n_radii,
                          const float* __restrict__ tol,
                          float* __restrict__ wval) {
    __shared__ float sh[4];
    float m = -1e30f;
    for (int i = threadIdx.x; i < n_radii; i += blockDim.x) m = fmaxf(m, radii[i]);
#pragma unroll
    for (int off = 32; off > 0; off >>= 1) m = fmaxf(m, __shfl_down(m, off, 64));
    if ((threadIdx.x & 63) == 0) sh[threadIdx.x >> 6] = m;
    __syncthreads();
    if (threadIdx.x == 0) {
        float mm = fmaxf(fmaxf(sh[0], sh[1]), fmaxf(sh[2], sh[3]));
        float tmax = -1e30f;
        for (int c = 0; c < N_CLASS_C; ++c) tmax = fmaxf(tmax, tol[c]);
        // any clash has dist < 2*rmax + tmax; margin for strictness
        wval[0] = fmaxf(2.0f * mm + tmax, 1e-2f) + 1e-3f;
    }
}

__global__ void prep_atoms(const float* __restrict__ coords,
                           const float* __restrict__ radii,
                           const int* __restrict__ names,
                           HAtom* __restrict__ atoms,
                           int n_atoms) {
    int i = blockIdx.x * blockDim.x + threadIdx.x;
    if (i < n_atoms) {
        HAtom a;
        a.x = __float2half(coords[3 * i + 0]);
        a.y = __float2half(coords[3 * i + 1]);
        a.z = __float2half(coords[3 * i + 2]);
        a.r = __float2half(radii[names[i]]);
        atoms[i] = a;
    }
}

// Per-atom 10-bit cell id: cx(3b) | cy(3b)<<3 | cz(4b)<<6, cell width w,
// clamped ranges x,y: [-4w,4w), z: [-8w,8w). 3 atoms packed per u32.
__global__ void prep_cells(const float* __restrict__ coords,
                           const float* __restrict__ wval,
                           unsigned* __restrict__ cellsg,
                           int n_words, int n_atoms) {
    float inv = 1.0f / wval[0];
    int t = blockIdx.x * blockDim.x + threadIdx.x;
    if (t < n_words) {
        unsigned word = 0;
#pragma unroll
        for (int s = 0; s < 3; ++s) {
            int i = 3 * t + s;
            unsigned c = 0;
            if (i < n_atoms) {
                float x = coords[3 * i + 0];
                float y = coords[3 * i + 1];
                float z = coords[3 * i + 2];
                int cx = (int)floorf(x * inv) + 4;
                int cy = (int)floorf(y * inv) + 4;
                int cz = (int)floorf(z * inv) + 8;
                cx = min(max(cx, 0), 7);
                cy = min(max(cy, 0), 7);
                cz = min(max(cz, 0), 15);
                c = (unsigned)cx | ((unsigned)cy << 3) | ((unsigned)cz << 6);
            }
            word |= c << (10 * s);
        }
        cellsg[t] = word;
    }
}

__device__ __forceinline__ unsigned cell_lookup(const unsigned* cells, int i) {
    // q = i / 3 (u32-safe magic), r = i % 3
    unsigned q = (unsigned)(((unsigned long long)(unsigned)i * 0xAAAAAAABull) >> 33);
    unsigned r = (unsigned)i - 3u * q;
    return (cells[q] >> (10u * r)) & 0x3FFu;
}

__device__ __forceinline__ void block_reduce_accum(float* s, float* accum) {
    __shared__ float sh[N_CLASS_C];
    if (threadIdx.x < N_CLASS_C) sh[threadIdx.x] = 0.0f;
    __syncthreads();
#pragma unroll
    for (int c = 0; c < N_CLASS_C; ++c) {
        float v = s[c];
#pragma unroll
        for (int off = 32; off > 0; off >>= 1) v += __shfl_down(v, off, 64);
        if ((threadIdx.x & 63) == 0 && v != 0.0f) atomicAdd(&sh[c], v);
    }
    __syncthreads();
    if (threadIdx.x < N_CLASS_C) {
        float v = sh[threadIdx.x];
        if (v != 0.0f) atomicAdd(&accum[threadIdx.x], v);
    }
}

__device__ __forceinline__ float hdist_base(const HAtom& A, const HAtom& B) {
    float dx = __half2float(A.x) - __half2float(B.x);
    float dy = __half2float(A.y) - __half2float(B.y);
    float dz = __half2float(A.z) - __half2float(B.z);
    float dist = sqrtf(dx * dx + dy * dy + dz * dz + 1e-12f);
    return (__half2float(A.r) + __half2float(B.r)) - dist;
}

// Main kernel: LDS-resident cell table filters pairs without any VMEM
// request; only ~5% of pairs issue the 2 scattered atom gathers.
__global__ __launch_bounds__(FILTER_BLOCK) void clash_filtered(
    const int* __restrict__ pairs,        // 2 * n_pairs
    const HAtom* __restrict__ atoms,
    const unsigned* __restrict__ cellsg,  // n_words packed cells
    const int* __restrict__ masks,        // N_CLASS * n_pairs
    const float* __restrict__ tol,
    float* __restrict__ accum,
    int n_pairs, int n_words) {
    __shared__ unsigned cells[MAX_WORDS];
    for (int i = threadIdx.x; i < n_words; i += FILTER_BLOCK)
        cells[i] = cellsg[i];

    float tc[N_CLASS_C];
#pragma unroll
    for (int c = 0; c < N_CLASS_C; ++c) tc[c] = tol[c];
    float tmax = tc[0];
#pragma unroll
    for (int c = 1; c < N_CLASS_C; ++c) tmax = fmaxf(tmax, tc[c]);

    float s[N_CLASS_C];
#pragma unroll
    for (int c = 0; c < N_CLASS_C; ++c) s[c] = 0.0f;

    __syncthreads();

    const vint2* pairs2 = reinterpret_cast<const vint2*>(pairs);
    const int stride = gridDim.x * FILTER_BLOCK;
    for (int p = blockIdx.x * FILTER_BLOCK + threadIdx.x; p < n_pairs; p += stride) {
        vint2 pr = pairs2[p];
        unsigned ca = cell_lookup(cells, pr.x);
        unsigned cb = cell_lookup(cells, pr.y);
        int dx = abs((int)(ca & 7u) - (int)(cb & 7u));
        int dy = abs((int)((ca >> 3) & 7u) - (int)((cb >> 3) & 7u));
        int dz = abs((int)((ca >> 6) & 15u) - (int)((cb >> 6) & 15u));
        // all non-negative: (dx|dy|dz) <= 1  <=>  dx<=1 && dy<=1 && dz<=1
        if ((dx | dy | dz) <= 1) {
            HAtom A = atoms[pr.x];
            HAtom B = atoms[pr.y];
            float base = hdist_base(A, B);
            if (base + tmax > 0.0f) {
#pragma unroll
                for (int c = 0; c < N_CLASS_C; ++c) {
                    if (masks[(size_t)c * n_pairs + p])
                        s[c] += fmaxf(base + tc[c], 0.0f);
                }
            }
        }
    }

    block_reduce_accum(s, accum);
}

__global__ void finalize(const float* __restrict__ accum,
                         const float* __restrict__ w,
                         float* __restrict__ out) {
    int c = threadIdx.x;
    if (c < N_CLASS_C) {
        float scale = expf(w[0]);
        out[c] = accum[c] * scale;
    }
}

// -------- fallback (tiny ws / oversized atom count): direct gather path --------
__global__ __launch_bounds__(256) void clash_fallback(
    const int* __restrict__ pairs,
    const float* __restrict__ coords,
    const float* __restrict__ radii,
    const int* __restrict__ names,
    const int* __restrict__ masks,
    const float* __restrict__ tol,
    float* __restrict__ accum,
    int n_pairs) {
    float tc[N_CLASS_C];
#pragma unroll
    for (int c = 0; c < N_CLASS_C; ++c) tc[c] = tol[c];
    float tmax = tc[0];
#pragma unroll
    for (int c = 1; c < N_CLASS_C; ++c) tmax = fmaxf(tmax, tc[c]);
    float s[N_CLASS_C];
#pragma unroll
    for (int c = 0; c < N_CLASS_C; ++c) s[c] = 0.0f;

    const int tid = blockIdx.x * blockDim.x + threadIdx.x;
    const int stride = gridDim.x * blockDim.x;
    for (int p = tid; p < n_pairs; p += stride) {
        int a0 = pairs[2 * p], a1 = pairs[2 * p + 1];
        float dx = coords[3 * a0] - coords[3 * a1];
        float dy = coords[3 * a0 + 1] - coords[3 * a1 + 1];
        float dz = coords[3 * a0 + 2] - coords[3 * a1 + 2];
        float dist = sqrtf(dx * dx + dy * dy + dz * dz + 1e-12f);
        float base = (radii[names[a0]] + radii[names[a1]]) - dist;
        if (base + tmax > 0.0f) {
#pragma unroll
            for (int c = 0; c < N_CLASS_C; ++c) {
                if (masks[(size_t)c * n_pairs + p])
                    s[c] += fmaxf(base + tc[c], 0.0f);
            }
        }
    }
    block_reduce_accum(s, accum);
}

extern "C" void kernel_launch(void* const* d_in, const int* in_sizes, int n_in,
                              void* d_out, int out_size, void* d_ws, size_t ws_size,
                              hipStream_t stream) {
    const float* coords = (const float*)d_in[0];
    const float* radii  = (const float*)d_in[1];
    const float* tol    = (const float*)d_in[2];
    const float* weight = (const float*)d_in[3];
    const int* names    = (const int*)d_in[4];
    const int* pairs    = (const int*)d_in[5];
    const int* masks    = (const int*)d_in[6];
    float* out = (float*)d_out;

    int n_atoms = in_sizes[4];
    int n_radii = in_sizes[1];
    int n_pairs = in_sizes[5] / 2;

    int n_words = (n_atoms + 2) / 3;
    size_t atoms_off = 256;
    size_t atoms_bytes = (size_t)n_atoms * sizeof(HAtom);
    size_t cells_off = (atoms_off + atoms_bytes + 255) & ~(size_t)255;
    size_t need = cells_off + (size_t)n_words * 4 + 64;

    if (ws_size >= need && n_words <= MAX_WORDS) {
        float* accum = (float*)d_ws;                       // 6 floats
        float* wval  = (float*)((char*)d_ws + 32);         // 1 float
        HAtom* atoms = (HAtom*)((char*)d_ws + atoms_off);
        unsigned* cellsg = (unsigned*)((char*)d_ws + cells_off);

        compute_w<<<1, 256, 0, stream>>>(radii, n_radii, tol, wval);
        prep_atoms<<<(n_atoms + 255) / 256, 256, 0, stream>>>(coords, radii, names,
                                                              atoms, n_atoms);
        prep_cells<<<(n_words + 255) / 256, 256, 0, stream>>>(coords, wval,
                                                              cellsg, n_words, n_atoms);
        zero_accum<<<1, 64, 0, stream>>>(accum);
        clash_filtered<<<FILTER_GRID, FILTER_BLOCK, 0, stream>>>(
            pairs, atoms, cellsg, masks, tol, accum, n_pairs, n_words);
        finalize<<<1, 64, 0, stream>>>(accum, weight, out);
    } else {
        float* accum = out;
        zero_accum<<<1, 64, 0, stream>>>(accum);
        clash_fallback<<<2048, 256, 0, stream>>>(pairs, coords, radii, names,
                                                 masks, tol, accum, n_pairs);
        finalize<<<1, 64, 0, stream>>>(accum, weight, out);
    }
}